// Round 3
// baseline (723.010 us; speedup 1.0000x reference)
//
#include <hip/hip_runtime.h>
#include <hip/hip_bf16.h>
#include <math.h>

#define NN 50000
#define EE 800000
#define DD 128
#define HH 8
#define DKK 16

typedef __attribute__((ext_vector_type(8))) short short8;
typedef __attribute__((ext_vector_type(4))) float f32x4;
typedef __attribute__((ext_vector_type(4))) unsigned short ushort4v;
typedef __attribute__((ext_vector_type(8))) unsigned short ushort8v;

static __device__ __forceinline__ unsigned short f2bf(float x) {
  __hip_bfloat16 h = __float2bfloat16(x);   // RNE
  return *reinterpret_cast<unsigned short*>(&h);
}
static __device__ __forceinline__ float bf2f(unsigned short u) {
  return __uint_as_float(((unsigned int)u) << 16);
}

// ---------------------------------------------------------------------------
// Prep: WkT[j][c] = bf16(Wk[c][j])  (L2-resident 32KB; B-frags read contiguous k)
// ---------------------------------------------------------------------------
__global__ void prep_wkt_kernel(const float* __restrict__ Wk,
                                unsigned short* __restrict__ WkT) {
  int c = blockIdx.x;
  int j = threadIdx.x;
  WkT[j * DD + c] = f2bf(Wk[c * DD + j]);
}

// ---------------------------------------------------------------------------
// Kernel 1: node projections  Qn = q @ Wq,  Vn = v @ Wv  (fp32 math, bf16 out)
// ---------------------------------------------------------------------------
__global__ __launch_bounds__(256) void node_proj_kernel(
    const float* __restrict__ q, const float* __restrict__ v,
    const float* __restrict__ Wq, const float* __restrict__ Wv,
    unsigned short* __restrict__ Qh, unsigned short* __restrict__ Vh)
{
  __shared__ float xl[64 * 130];
  const int tid = threadIdx.x;
  const int n0 = blockIdx.x * 64;
  const int jg = tid & 15;
  const int rg = tid >> 4;

  const float* X[2] = { q, v };
  const float* W[2] = { Wq, Wv };
  unsigned short* O[2] = { Qh, Vh };

  for (int m = 0; m < 2; ++m) {
    __syncthreads();
    const float* x = X[m];
    #pragma unroll 4
    for (int p = 0; p < 32; ++p) {
      int flat = p * 256 + tid;
      int i = flat >> 7, c = flat & 127;
      int n = n0 + i;
      xl[i * 130 + c] = (n < NN) ? x[(size_t)n * DD + c] : 0.0f;
    }
    __syncthreads();

    const float* Wm = W[m];
    float acc[4][8];
    #pragma unroll
    for (int r = 0; r < 4; ++r)
      #pragma unroll
      for (int j = 0; j < 8; ++j) acc[r][j] = 0.0f;

    for (int c = 0; c < 128; ++c) {
      float4 w0 = *(const float4*)&Wm[c * DD + jg * 8];
      float4 w1 = *(const float4*)&Wm[c * DD + jg * 8 + 4];
      #pragma unroll
      for (int r = 0; r < 4; ++r) {
        float xr = xl[(rg * 4 + r) * 130 + c];
        acc[r][0] = fmaf(xr, w0.x, acc[r][0]);
        acc[r][1] = fmaf(xr, w0.y, acc[r][1]);
        acc[r][2] = fmaf(xr, w0.z, acc[r][2]);
        acc[r][3] = fmaf(xr, w0.w, acc[r][3]);
        acc[r][4] = fmaf(xr, w1.x, acc[r][4]);
        acc[r][5] = fmaf(xr, w1.y, acc[r][5]);
        acc[r][6] = fmaf(xr, w1.z, acc[r][6]);
        acc[r][7] = fmaf(xr, w1.w, acc[r][7]);
      }
    }

    unsigned short* o = O[m];
    #pragma unroll
    for (int r = 0; r < 4; ++r) {
      int n = n0 + rg * 4 + r;
      if (n < NN) {
        ushort8v o8;
        #pragma unroll
        for (int j = 0; j < 8; ++j) o8[j] = f2bf(acc[r][j]);
        *(ushort8v*)&o[(size_t)n * DD + jg * 8] = o8;
      }
    }
  }
}

// ---------------------------------------------------------------------------
// Kernel 2: fused edge attention.
// LDS: single 34816B union (kke bf16 [64][136] | ke bf16 [64][136] | He f32
// [64][132]) + indices -> 35.3KB -> 4 blocks/CU (32 waves, max occupancy).
// WkT read directly from global (L1/L2-resident, shared by all blocks).
// ---------------------------------------------------------------------------
__global__ __launch_bounds__(512, 8) void edge_attn_kernel(
    const float* __restrict__ k, const float* __restrict__ e,
    const int* __restrict__ src, const int* __restrict__ dst,
    const unsigned short* __restrict__ WkT,
    const unsigned short* __restrict__ Qh, const unsigned short* __restrict__ Vh,
    float* __restrict__ out)
{
  __shared__ __align__(16) unsigned short smem[2 * 64 * 136];  // 34816 B
  __shared__ int s_src[64], s_dst[64];

  unsigned short* kke_l = smem;             // [64][136] bf16
  unsigned short* ke_l  = smem + 64 * 136;  // [64][136] bf16
  float* He = (float*)smem;                 // [64][132] f32 (33792 B)

  const int tid = threadIdx.x;
  const size_t e0 = (size_t)blockIdx.x * 64;

  if (tid < 64) {
    s_src[tid] = src[e0 + tid];
    s_dst[tid] = dst[e0 + tid];
  }
  __syncthreads();   // s_src visible before gather

  // ---- stage kke[i][c] = bf16(k[src_i][c] + e[edge][c]) ----
  #pragma unroll
  for (int p = 0; p < 4; ++p) {
    int f = p * 512 + tid;              // 2048 chunks of 4 floats
    int i = f >> 5, c4 = f & 31;
    float4 kv = *(const float4*)&k[(size_t)s_src[i] * DD + c4 * 4];
    float4 ev = *(const float4*)&e[(e0 + i) * DD + c4 * 4];
    ushort4v o = { f2bf(kv.x + ev.x), f2bf(kv.y + ev.y),
                   f2bf(kv.z + ev.z), f2bf(kv.w + ev.w) };
    *(ushort4v*)&kke_l[i * 136 + c4 * 4] = o;
  }
  __syncthreads();

  // ---- phase 1: Ke = kke @ Wk via MFMA; B-frags straight from global ----
  {
    const int lane = tid & 63, wid = tid >> 6;
    const int rg = wid & 3, cg = wid >> 2;
    const int lr = lane & 15, lg = lane >> 4;

    f32x4 acc0 = {0.f,0.f,0.f,0.f}, acc1 = {0.f,0.f,0.f,0.f};
    f32x4 acc2 = {0.f,0.f,0.f,0.f}, acc3 = {0.f,0.f,0.f,0.f};

    const unsigned short* Ab = &kke_l[(rg * 16 + lr) * 136];
    const unsigned short* B0 = &WkT[(size_t)(cg * 64 +  0 + lr) * DD];
    const unsigned short* B1 = &WkT[(size_t)(cg * 64 + 16 + lr) * DD];
    const unsigned short* B2 = &WkT[(size_t)(cg * 64 + 32 + lr) * DD];
    const unsigned short* B3 = &WkT[(size_t)(cg * 64 + 48 + lr) * DD];

    #pragma unroll
    for (int kk = 0; kk < 4; ++kk) {
      const int kof = kk * 32 + lg * 8;
      short8 a = *(const short8*)(Ab + kof);
      acc0 = __builtin_amdgcn_mfma_f32_16x16x32_bf16(a, *(const short8*)(B0 + kof), acc0, 0, 0, 0);
      acc1 = __builtin_amdgcn_mfma_f32_16x16x32_bf16(a, *(const short8*)(B1 + kof), acc1, 0, 0, 0);
      acc2 = __builtin_amdgcn_mfma_f32_16x16x32_bf16(a, *(const short8*)(B2 + kof), acc2, 0, 0, 0);
      acc3 = __builtin_amdgcn_mfma_f32_16x16x32_bf16(a, *(const short8*)(B3 + kof), acc3, 0, 0, 0);
    }

    // D layout: col = lane&15, row = (lane>>4)*4 + r  (verified r2, absmax ok)
    const int r0 = rg * 16 + lg * 4;
    const int cb = cg * 64 + lr;
    #pragma unroll
    for (int r = 0; r < 4; ++r) {
      ke_l[(r0 + r) * 136 + cb +  0] = f2bf(acc0[r]);
      ke_l[(r0 + r) * 136 + cb + 16] = f2bf(acc1[r]);
      ke_l[(r0 + r) * 136 + cb + 32] = f2bf(acc2[r]);
      ke_l[(r0 + r) * 136 + cb + 48] = f2bf(acc3[r]);
    }
  }
  __syncthreads();   // Ke ready; kke dead

  // ---- phase 2a: per (edge i, head h) scores + softmax (reads ke_l) ----
  const int i = tid >> 3, h = tid & 7;
  const int sn = s_src[i], dn = s_dst[i];

  float sc[8];
  {
    float Qr[16];
    ushort8v q0 = *(const ushort8v*)&Qh[(size_t)dn * DD + h * DKK];
    ushort8v q1 = *(const ushort8v*)&Qh[(size_t)dn * DD + h * DKK + 8];
    #pragma unroll
    for (int t = 0; t < 8; ++t) { Qr[t] = bf2f(q0[t]); Qr[8 + t] = bf2f(q1[t]); }

    #pragma unroll
    for (int g = 0; g < 8; ++g) {
      const ushort8v* kp = (const ushort8v*)&ke_l[i * 136 + g * DKK];
      ushort8v k0 = kp[0], k1 = kp[1];
      float a = 0.0f;
      #pragma unroll
      for (int t = 0; t < 8; ++t) a = fmaf(Qr[t], bf2f(k0[t]), a);
      #pragma unroll
      for (int t = 0; t < 8; ++t) a = fmaf(Qr[8 + t], bf2f(k1[t]), a);
      a *= 0.25f;
      sc[g] = (a >= 0.0f) ? a : 0.01f * a;
    }

    float mx = sc[0];
    #pragma unroll
    for (int g = 1; g < 8; ++g) mx = fmaxf(mx, sc[g]);
    float sum = 0.0f;
    #pragma unroll
    for (int g = 0; g < 8; ++g) { sc[g] = __expf(sc[g] - mx); sum += sc[g]; }
    float rs = 1.0f / sum;
    #pragma unroll
    for (int g = 0; g < 8; ++g) sc[g] *= rs;
  }
  __syncthreads();   // all ke_l reads done -> He may overwrite smem

  // ---- phase 2b: He = A @ Ve (bf16 V gather), stage into smem ----
  {
    float he[16];
    #pragma unroll
    for (int d = 0; d < 16; ++d) he[d] = 0.0f;
    #pragma unroll
    for (int g = 0; g < 8; ++g) {
      float a = sc[g];
      ushort8v v0 = *(const ushort8v*)&Vh[(size_t)sn * DD + g * DKK];
      ushort8v v1 = *(const ushort8v*)&Vh[(size_t)sn * DD + g * DKK + 8];
      #pragma unroll
      for (int t = 0; t < 8; ++t) {
        he[t]     = fmaf(a, bf2f(v0[t]), he[t]);
        he[8 + t] = fmaf(a, bf2f(v1[t]), he[8 + t]);
      }
    }
    #pragma unroll
    for (int d0 = 0; d0 < 4; ++d0) {
      float4 t = { he[d0 * 4], he[d0 * 4 + 1], he[d0 * 4 + 2], he[d0 * 4 + 3] };
      *(float4*)&He[i * 132 + h * DKK + d0 * 4] = t;
    }
  }
  __syncthreads();

  // ---- coalesced atomic scatter: out[dst_i] += He[i] ----
  #pragma unroll 4
  for (int p = 0; p < 16; ++p) {
    int flat = p * 512 + tid;
    int i2 = flat >> 7, d = flat & 127;
    atomicAdd(&out[(size_t)s_dst[i2] * DD + d], He[i2 * 132 + d]);
  }
}

// ---------------------------------------------------------------------------
extern "C" void kernel_launch(void* const* d_in, const int* in_sizes, int n_in,
                              void* d_out, int out_size, void* d_ws, size_t ws_size,
                              hipStream_t stream) {
  const float* q  = (const float*)d_in[0];
  const float* k  = (const float*)d_in[1];
  const float* v  = (const float*)d_in[2];
  const float* e  = (const float*)d_in[3];
  const int*   src = (const int*)d_in[4];
  const int*   dst = (const int*)d_in[5];
  const float* Wq = (const float*)d_in[6];
  const float* Wk = (const float*)d_in[7];
  const float* Wv = (const float*)d_in[8];

  float* out = (float*)d_out;
  unsigned short* Qh  = (unsigned short*)d_ws;                  // [N][128] bf16
  unsigned short* Vh  = Qh + (size_t)NN * DD;                   // [N][128] bf16
  unsigned short* WkT = Vh + (size_t)NN * DD;                   // [128][128] bf16

  hipMemsetAsync(d_out, 0, (size_t)NN * DD * sizeof(float), stream);
  prep_wkt_kernel<<<DD, DD, 0, stream>>>(Wk, WkT);
  node_proj_kernel<<<(NN + 63) / 64, 256, 0, stream>>>(q, v, Wq, Wv, Qh, Vh);
  edge_attn_kernel<<<EE / 64, 512, 0, stream>>>(k, e, src, dst, WkT, Qh, Vh, out);
}

// Round 4
// 521.888 us; speedup vs baseline: 1.3854x; 1.3854x over previous
//
#include <hip/hip_runtime.h>
#include <hip/hip_bf16.h>
#include <math.h>

#define NN 50000
#define EE 800000
#define DD 128
#define HH 8
#define DKK 16

typedef __attribute__((ext_vector_type(8))) short short8;
typedef __attribute__((ext_vector_type(4))) float f32x4;
typedef __attribute__((ext_vector_type(4))) unsigned short ushort4v;
typedef __attribute__((ext_vector_type(8))) unsigned short ushort8v;

static __device__ __forceinline__ unsigned short f2bf(float x) {
  __hip_bfloat16 h = __float2bfloat16(x);   // RNE
  return *reinterpret_cast<unsigned short*>(&h);
}
static __device__ __forceinline__ float bf2f(unsigned short u) {
  return __uint_as_float(((unsigned int)u) << 16);
}

// ---------------------------------------------------------------------------
// Prep: WT[j][c] = bf16(W[c][j]) for Wq, Wk, Wv (each 32KB bf16, L2-resident)
// ---------------------------------------------------------------------------
__global__ void prep_w_kernel(const float* __restrict__ Wq,
                              const float* __restrict__ Wk,
                              const float* __restrict__ Wv,
                              unsigned short* __restrict__ WqT,
                              unsigned short* __restrict__ WkT,
                              unsigned short* __restrict__ WvT) {
  int c = blockIdx.x & 127;
  int m = blockIdx.x >> 7;          // 0,1,2
  int j = threadIdx.x;
  const float* W = (m == 0) ? Wq : (m == 1) ? Wk : Wv;
  unsigned short* o = (m == 0) ? WqT : (m == 1) ? WkT : WvT;
  o[j * DD + c] = f2bf(W[c * DD + j]);
}

// ---------------------------------------------------------------------------
// Kernel 1: node projections via MFMA.  Qh = bf16(q @ Wq), Vh = bf16(v @ Wv).
// 64 nodes/block, 512 threads, LDS 17.4KB.
// ---------------------------------------------------------------------------
__global__ __launch_bounds__(512) void node_proj_kernel(
    const float* __restrict__ q, const float* __restrict__ v,
    const unsigned short* __restrict__ WqT, const unsigned short* __restrict__ WvT,
    unsigned short* __restrict__ Qh, unsigned short* __restrict__ Vh)
{
  __shared__ __align__(16) unsigned short xl[64 * 136];
  const int tid = threadIdx.x;
  const int n0 = blockIdx.x * 64;

  for (int m = 0; m < 2; ++m) {
    const float* x = m ? v : q;
    const unsigned short* WT = m ? WvT : WqT;
    unsigned short* o = m ? Vh : Qh;

    __syncthreads();                    // protect xl reuse across m
    #pragma unroll
    for (int p = 0; p < 4; ++p) {
      int f = p * 512 + tid;            // 2048 chunks of 4 floats
      int i = f >> 5, c4 = f & 31;
      int n = n0 + i;
      float4 t = (n < NN) ? *(const float4*)&x[(size_t)n * DD + c4 * 4]
                          : float4{0.f, 0.f, 0.f, 0.f};
      ushort4v u = { f2bf(t.x), f2bf(t.y), f2bf(t.z), f2bf(t.w) };
      *(ushort4v*)&xl[i * 136 + c4 * 4] = u;
    }
    __syncthreads();

    const int lane = tid & 63, wid = tid >> 6;
    const int rg = wid & 3, cg = wid >> 2;
    const int lr = lane & 15, lg = lane >> 4;

    f32x4 acc0 = {0.f,0.f,0.f,0.f}, acc1 = {0.f,0.f,0.f,0.f};
    f32x4 acc2 = {0.f,0.f,0.f,0.f}, acc3 = {0.f,0.f,0.f,0.f};

    const unsigned short* Ab = &xl[(rg * 16 + lr) * 136];
    const unsigned short* B0 = &WT[(size_t)(cg * 64 +  0 + lr) * DD];
    const unsigned short* B1 = &WT[(size_t)(cg * 64 + 16 + lr) * DD];
    const unsigned short* B2 = &WT[(size_t)(cg * 64 + 32 + lr) * DD];
    const unsigned short* B3 = &WT[(size_t)(cg * 64 + 48 + lr) * DD];

    #pragma unroll
    for (int kk = 0; kk < 4; ++kk) {
      const int kof = kk * 32 + lg * 8;
      short8 a = *(const short8*)(Ab + kof);
      acc0 = __builtin_amdgcn_mfma_f32_16x16x32_bf16(a, *(const short8*)(B0 + kof), acc0, 0, 0, 0);
      acc1 = __builtin_amdgcn_mfma_f32_16x16x32_bf16(a, *(const short8*)(B1 + kof), acc1, 0, 0, 0);
      acc2 = __builtin_amdgcn_mfma_f32_16x16x32_bf16(a, *(const short8*)(B2 + kof), acc2, 0, 0, 0);
      acc3 = __builtin_amdgcn_mfma_f32_16x16x32_bf16(a, *(const short8*)(B3 + kof), acc3, 0, 0, 0);
    }

    const int r0 = rg * 16 + lg * 4;
    const int cb = cg * 64 + lr;
    #pragma unroll
    for (int r = 0; r < 4; ++r) {
      int n = n0 + r0 + r;
      if (n < NN) {
        unsigned short* orow = &o[(size_t)n * DD + cb];
        orow[ 0] = f2bf(acc0[r]);
        orow[16] = f2bf(acc1[r]);
        orow[32] = f2bf(acc2[r]);
        orow[48] = f2bf(acc3[r]);
      }
    }
  }
}

// ---------------------------------------------------------------------------
// Kernel 2: fused edge attention. LDS 35.3KB union; WkT/Qh/Vh from global
// (L2/L3-resident). launch_bounds(512,6): VGPR budget ~85 -> spill-free,
// 3-4 blocks/CU.
// ---------------------------------------------------------------------------
__global__ __launch_bounds__(512, 6) void edge_attn_kernel(
    const float* __restrict__ k, const float* __restrict__ e,
    const int* __restrict__ src, const int* __restrict__ dst,
    const unsigned short* __restrict__ WkT,
    const unsigned short* __restrict__ Qh, const unsigned short* __restrict__ Vh,
    float* __restrict__ out)
{
  __shared__ __align__(16) unsigned short smem[2 * 64 * 136];  // 34816 B
  __shared__ int s_src[64], s_dst[64];

  unsigned short* kke_l = smem;             // [64][136] bf16
  unsigned short* ke_l  = smem + 64 * 136;  // [64][136] bf16
  float* He = (float*)smem;                 // [64][132] f32 (33792 B)

  const int tid = threadIdx.x;
  const size_t e0 = (size_t)blockIdx.x * 64;

  if (tid < 64) {
    s_src[tid] = src[e0 + tid];
    s_dst[tid] = dst[e0 + tid];
  }
  __syncthreads();   // s_src visible before gather

  // ---- stage kke[i][c] = bf16(k[src_i][c] + e[edge][c]) ----
  #pragma unroll
  for (int p = 0; p < 4; ++p) {
    int f = p * 512 + tid;              // 2048 chunks of 4 floats
    int i = f >> 5, c4 = f & 31;
    float4 kv = *(const float4*)&k[(size_t)s_src[i] * DD + c4 * 4];
    float4 ev = *(const float4*)&e[(e0 + i) * DD + c4 * 4];
    ushort4v o = { f2bf(kv.x + ev.x), f2bf(kv.y + ev.y),
                   f2bf(kv.z + ev.z), f2bf(kv.w + ev.w) };
    *(ushort4v*)&kke_l[i * 136 + c4 * 4] = o;
  }
  __syncthreads();

  // ---- phase 1: Ke = kke @ Wk via MFMA; B-frags from global WkT ----
  {
    const int lane = tid & 63, wid = tid >> 6;
    const int rg = wid & 3, cg = wid >> 2;
    const int lr = lane & 15, lg = lane >> 4;

    f32x4 acc0 = {0.f,0.f,0.f,0.f}, acc1 = {0.f,0.f,0.f,0.f};
    f32x4 acc2 = {0.f,0.f,0.f,0.f}, acc3 = {0.f,0.f,0.f,0.f};

    const unsigned short* Ab = &kke_l[(rg * 16 + lr) * 136];
    const unsigned short* B0 = &WkT[(size_t)(cg * 64 +  0 + lr) * DD];
    const unsigned short* B1 = &WkT[(size_t)(cg * 64 + 16 + lr) * DD];
    const unsigned short* B2 = &WkT[(size_t)(cg * 64 + 32 + lr) * DD];
    const unsigned short* B3 = &WkT[(size_t)(cg * 64 + 48 + lr) * DD];

    #pragma unroll
    for (int kk = 0; kk < 4; ++kk) {
      const int kof = kk * 32 + lg * 8;
      short8 a = *(const short8*)(Ab + kof);
      acc0 = __builtin_amdgcn_mfma_f32_16x16x32_bf16(a, *(const short8*)(B0 + kof), acc0, 0, 0, 0);
      acc1 = __builtin_amdgcn_mfma_f32_16x16x32_bf16(a, *(const short8*)(B1 + kof), acc1, 0, 0, 0);
      acc2 = __builtin_amdgcn_mfma_f32_16x16x32_bf16(a, *(const short8*)(B2 + kof), acc2, 0, 0, 0);
      acc3 = __builtin_amdgcn_mfma_f32_16x16x32_bf16(a, *(const short8*)(B3 + kof), acc3, 0, 0, 0);
    }

    const int r0 = rg * 16 + lg * 4;
    const int cb = cg * 64 + lr;
    #pragma unroll
    for (int r = 0; r < 4; ++r) {
      ke_l[(r0 + r) * 136 + cb +  0] = f2bf(acc0[r]);
      ke_l[(r0 + r) * 136 + cb + 16] = f2bf(acc1[r]);
      ke_l[(r0 + r) * 136 + cb + 32] = f2bf(acc2[r]);
      ke_l[(r0 + r) * 136 + cb + 48] = f2bf(acc3[r]);
    }
  }
  __syncthreads();   // Ke ready; kke dead

  // ---- phase 2a: per (edge i, head h) scores + softmax (reads ke_l) ----
  const int i = tid >> 3, h = tid & 7;
  const int sn = s_src[i], dn = s_dst[i];

  float sc[8];
  {
    float Qr[16];
    ushort8v q0 = *(const ushort8v*)&Qh[(size_t)dn * DD + h * DKK];
    ushort8v q1 = *(const ushort8v*)&Qh[(size_t)dn * DD + h * DKK + 8];
    #pragma unroll
    for (int t = 0; t < 8; ++t) { Qr[t] = bf2f(q0[t]); Qr[8 + t] = bf2f(q1[t]); }

    #pragma unroll
    for (int g = 0; g < 8; ++g) {
      const ushort8v* kp = (const ushort8v*)&ke_l[i * 136 + g * DKK];
      ushort8v k0 = kp[0], k1 = kp[1];
      float a = 0.0f;
      #pragma unroll
      for (int t = 0; t < 8; ++t) a = fmaf(Qr[t], bf2f(k0[t]), a);
      #pragma unroll
      for (int t = 0; t < 8; ++t) a = fmaf(Qr[8 + t], bf2f(k1[t]), a);
      a *= 0.25f;
      sc[g] = (a >= 0.0f) ? a : 0.01f * a;
    }

    float mx = sc[0];
    #pragma unroll
    for (int g = 1; g < 8; ++g) mx = fmaxf(mx, sc[g]);
    float sum = 0.0f;
    #pragma unroll
    for (int g = 0; g < 8; ++g) { sc[g] = __expf(sc[g] - mx); sum += sc[g]; }
    float rs = 1.0f / sum;
    #pragma unroll
    for (int g = 0; g < 8; ++g) sc[g] *= rs;
  }
  __syncthreads();   // all ke_l reads done -> He may overwrite smem

  // ---- phase 2b: He = A @ Ve (bf16 V gather), stage into smem ----
  {
    float he[16];
    #pragma unroll
    for (int d = 0; d < 16; ++d) he[d] = 0.0f;
    #pragma unroll
    for (int g = 0; g < 8; ++g) {
      float a = sc[g];
      ushort8v v0 = *(const ushort8v*)&Vh[(size_t)sn * DD + g * DKK];
      ushort8v v1 = *(const ushort8v*)&Vh[(size_t)sn * DD + g * DKK + 8];
      #pragma unroll
      for (int t = 0; t < 8; ++t) {
        he[t]     = fmaf(a, bf2f(v0[t]), he[t]);
        he[8 + t] = fmaf(a, bf2f(v1[t]), he[8 + t]);
      }
    }
    #pragma unroll
    for (int d0 = 0; d0 < 4; ++d0) {
      float4 t = { he[d0 * 4], he[d0 * 4 + 1], he[d0 * 4 + 2], he[d0 * 4 + 3] };
      *(float4*)&He[i * 132 + h * DKK + d0 * 4] = t;
    }
  }
  __syncthreads();

  // ---- coalesced atomic scatter: out[dst_i] += He[i] ----
  for (int p = 0; p < 16; ++p) {
    int flat = p * 512 + tid;
    int i2 = flat >> 7, d = flat & 127;
    atomicAdd(&out[(size_t)s_dst[i2] * DD + d], He[i2 * 132 + d]);
  }
}

// ---------------------------------------------------------------------------
extern "C" void kernel_launch(void* const* d_in, const int* in_sizes, int n_in,
                              void* d_out, int out_size, void* d_ws, size_t ws_size,
                              hipStream_t stream) {
  const float* q  = (const float*)d_in[0];
  const float* k  = (const float*)d_in[1];
  const float* v  = (const float*)d_in[2];
  const float* e  = (const float*)d_in[3];
  const int*   src = (const int*)d_in[4];
  const int*   dst = (const int*)d_in[5];
  const float* Wq = (const float*)d_in[6];
  const float* Wk = (const float*)d_in[7];
  const float* Wv = (const float*)d_in[8];

  float* out = (float*)d_out;
  unsigned short* Qh  = (unsigned short*)d_ws;                  // [N][128] bf16
  unsigned short* Vh  = Qh + (size_t)NN * DD;                   // [N][128] bf16
  unsigned short* WqT = Vh + (size_t)NN * DD;                   // [128][128] bf16
  unsigned short* WkT = WqT + DD * DD;
  unsigned short* WvT = WkT + DD * DD;

  hipMemsetAsync(d_out, 0, (size_t)NN * DD * sizeof(float), stream);
  prep_w_kernel<<<3 * DD, DD, 0, stream>>>(Wq, Wk, Wv, WqT, WkT, WvT);
  node_proj_kernel<<<(NN + 63) / 64, 512, 0, stream>>>(q, v, WqT, WvT, Qh, Vh);
  edge_attn_kernel<<<EE / 64, 512, 0, stream>>>(k, e, src, dst, WkT, Qh, Vh, out);
}